// Round 2
// baseline (907.555 us; speedup 1.0000x reference)
//
#include <hip/hip_runtime.h>
#include <math.h>

// Problem constants
// B=512, S=256, IN_ACT=16, OUT_ACT=14, EMB=256, HID=1024, FEAT=512
// d_out layout (floats): h1 @0 (524288) | c1 @524288 | alpha @1048576 (131072) | logit @1179648 (7168)
// d_ws layout (floats):
//   wcat  @0        : [512][2048] f32 (cols 0..1023 = weighted, cols 1024..2047 = h1)
//   gates @1048576  : [512][4096] f32
//   xh    @3145728  : [512][1792] f32 (dead after gates GEMM)
//   target@3145728  : [512][1024] (reuses xh region)
//   htld  @3670016  : [512][1024]
// total 4194304 floats = 16 MB

typedef __bf16 bf16x8 __attribute__((ext_vector_type(8)));
typedef float f32x4 __attribute__((ext_vector_type(4)));

__device__ __forceinline__ float sigmoidf_(float x) { return 1.0f / (1.0f + expf(-x)); }

// ---------------- build xh = [emb(action) | feature | h0] : [512][1792] f32 ----------------
__global__ __launch_bounds__(256) void k_build_xh(
    const int* __restrict__ action, const float* __restrict__ feature,
    const float* __restrict__ h0, const float* __restrict__ emb,
    float* __restrict__ xh)
{
    int idx = blockIdx.x * 256 + threadIdx.x;      // 512*448 total (float4 granules)
    if (idx >= 512 * 448) return;
    int b = idx / 448;
    int k = (idx % 448) * 4;
    float4 v;
    if (k < 256)      v = *(const float4*)(emb + action[b] * 256 + k);
    else if (k < 768) v = *(const float4*)(feature + b * 512 + (k - 256));
    else              v = *(const float4*)(h0 + b * 1024 + (k - 768));
    *(float4*)(xh + b * 1792 + k) = v;
}

// ---------------- bf16 MFMA NT GEMM: C[M,N] = A[M,K]@B[N,K]^T, f32 in / f32 out ----------------
// 64x64 tile, BK=32, 256 threads (4 waves as 2x2 of 32x32), f32->bf16 convert during LDS staging.
// LDS row stride 40 bf16 (80B): frag ds_read_b128 start banks {0,20,8,28,16,4,24,12} -> 2-way = free.
template<bool BIAS2, bool TANH>
__global__ __launch_bounds__(256) void k_gemm_mfma(
    const float* __restrict__ A1, int lda1, const float* __restrict__ B1, int ldb1, int K1,
    const float* __restrict__ A2, int lda2, const float* __restrict__ B2, int ldb2, int K2,
    float* __restrict__ C, int ldc,
    const float* __restrict__ bias1, const float* __restrict__ bias2)
{
    __shared__ alignas(16) __bf16 As[64 * 40];
    __shared__ alignas(16) __bf16 Bs[64 * 40];
    const int tid = threadIdx.x;
    const int lane = tid & 63, wave = tid >> 6;
    const int wm = wave >> 1, wn = wave & 1;
    const int bm = blockIdx.x * 64, bn = blockIdx.y * 64;
    const int srow = tid >> 2;        // staging row 0..63
    const int sk = (tid & 3) * 8;     // staging k-offset: 0,8,16,24

    f32x4 acc[2][2] = {};

    #pragma unroll
    for (int phase = 0; phase < 2; ++phase) {
        const int K = phase ? K2 : K1;
        if (K == 0) continue;
        const float* A  = phase ? A2 : A1;
        const float* Bp = phase ? B2 : B1;
        const int lda = phase ? lda2 : lda1;
        const int ldb = phase ? ldb2 : ldb1;
        const float* Ag = A  + (long)(bm + srow) * lda + sk;
        const float* Bg = Bp + (long)(bn + srow) * ldb + sk;

        for (int k0 = 0; k0 < K; k0 += 32) {
            float4 a0 = *(const float4*)(Ag + k0);
            float4 a1 = *(const float4*)(Ag + k0 + 4);
            float4 b0 = *(const float4*)(Bg + k0);
            float4 b1 = *(const float4*)(Bg + k0 + 4);
            __syncthreads();
            bf16x8 pa, pb;
            pa[0] = (__bf16)a0.x; pa[1] = (__bf16)a0.y; pa[2] = (__bf16)a0.z; pa[3] = (__bf16)a0.w;
            pa[4] = (__bf16)a1.x; pa[5] = (__bf16)a1.y; pa[6] = (__bf16)a1.z; pa[7] = (__bf16)a1.w;
            pb[0] = (__bf16)b0.x; pb[1] = (__bf16)b0.y; pb[2] = (__bf16)b0.z; pb[3] = (__bf16)b0.w;
            pb[4] = (__bf16)b1.x; pb[5] = (__bf16)b1.y; pb[6] = (__bf16)b1.z; pb[7] = (__bf16)b1.w;
            *(bf16x8*)&As[srow * 40 + sk] = pa;
            *(bf16x8*)&Bs[srow * 40 + sk] = pb;
            __syncthreads();

            const int ar = (wm * 32 + (lane & 15)) * 40 + (lane >> 4) * 8;
            const int br = (wn * 32 + (lane & 15)) * 40 + (lane >> 4) * 8;
            bf16x8 af0 = *(const bf16x8*)&As[ar];
            bf16x8 af1 = *(const bf16x8*)&As[ar + 16 * 40];
            bf16x8 bf0 = *(const bf16x8*)&Bs[br];
            bf16x8 bf1 = *(const bf16x8*)&Bs[br + 16 * 40];
            acc[0][0] = __builtin_amdgcn_mfma_f32_16x16x32_bf16(af0, bf0, acc[0][0], 0, 0, 0);
            acc[0][1] = __builtin_amdgcn_mfma_f32_16x16x32_bf16(af0, bf1, acc[0][1], 0, 0, 0);
            acc[1][0] = __builtin_amdgcn_mfma_f32_16x16x32_bf16(af1, bf0, acc[1][0], 0, 0, 0);
            acc[1][1] = __builtin_amdgcn_mfma_f32_16x16x32_bf16(af1, bf1, acc[1][1], 0, 0, 0);
        }
    }

    // epilogue: C/D layout col=lane&15, row=(lane>>4)*4+reg (verified m89)
    const int mrow = bm + wm * 32 + (lane >> 4) * 4;
    const int ncol = bn + wn * 32 + (lane & 15);
    #pragma unroll
    for (int fm = 0; fm < 2; ++fm) {
        #pragma unroll
        for (int fn = 0; fn < 2; ++fn) {
            const int c = ncol + fn * 16;
            float badd = 0.f;
            if (BIAS2) badd = bias1[c] + bias2[c];
            #pragma unroll
            for (int i = 0; i < 4; ++i) {
                float v = acc[fm][fn][i] + badd;
                if (TANH) v = tanhf(v);
                C[(long)(mrow + fm * 16 + i) * ldc + c] = v;
            }
        }
    }
}

// ---------------- f32 tiled NT GEMM (kept for W_in: feeds peaked softmax, needs f32 accuracy) ----
__global__ __launch_bounds__(256) void k_gemm_nt_f32(
    const float* __restrict__ A, int lda, const float* __restrict__ B, int ldb, int K,
    float* __restrict__ C, int ldc)
{
    __shared__ float As[16][68];
    __shared__ float Bs[16][68];
    const int tid = threadIdx.x;
    const int tx = tid & 15, ty = tid >> 4;
    const int bm = blockIdx.x * 64, bn = blockIdx.y * 64;
    const int lrow = tid >> 2;
    const int lk = (tid & 3) << 2;
    float acc[4][4] = {};
    const float* Ag = A + (long)(bm + lrow) * lda + lk;
    const float* Bg = B + (long)(bn + lrow) * ldb + lk;
    for (int k0 = 0; k0 < K; k0 += 16) {
        float4 av = *(const float4*)(Ag + k0);
        float4 bv = *(const float4*)(Bg + k0);
        __syncthreads();
        As[lk + 0][lrow] = av.x; As[lk + 1][lrow] = av.y;
        As[lk + 2][lrow] = av.z; As[lk + 3][lrow] = av.w;
        Bs[lk + 0][lrow] = bv.x; Bs[lk + 1][lrow] = bv.y;
        Bs[lk + 2][lrow] = bv.z; Bs[lk + 3][lrow] = bv.w;
        __syncthreads();
        #pragma unroll
        for (int k = 0; k < 16; ++k) {
            float4 a4 = *(const float4*)&As[k][ty * 4];
            float4 b4 = *(const float4*)&Bs[k][tx * 4];
            float am[4] = {a4.x, a4.y, a4.z, a4.w};
            float bb[4] = {b4.x, b4.y, b4.z, b4.w};
            #pragma unroll
            for (int mi = 0; mi < 4; ++mi)
                #pragma unroll
                for (int ni = 0; ni < 4; ++ni)
                    acc[mi][ni] = fmaf(am[mi], bb[ni], acc[mi][ni]);
        }
    }
    const int row = bm + ty * 4, col = bn + tx * 4;
    #pragma unroll
    for (int mi = 0; mi < 4; ++mi) {
        float4 o = {acc[mi][0], acc[mi][1], acc[mi][2], acc[mi][3]};
        *(float4*)(C + (long)(row + mi) * ldc + col) = o;
    }
}

// ---------------- LSTM cell elementwise ----------------
__global__ __launch_bounds__(256) void k_lstm(
    const float* __restrict__ gates, const float* __restrict__ c0,
    float* __restrict__ h1_out, float* __restrict__ c1_out, float* __restrict__ hcat)
{
    int idx = blockIdx.x * 256 + threadIdx.x;   // 512*256 (float4 granules over H)
    int b = idx >> 8;
    int h = (idx & 255) << 2;
    const float* g = gates + b * 4096 + h;
    float4 gi = *(const float4*)(g);
    float4 gf = *(const float4*)(g + 1024);
    float4 gg = *(const float4*)(g + 2048);
    float4 go = *(const float4*)(g + 3072);
    float4 c0v = *(const float4*)(c0 + b * 1024 + h);
    float4 c1, h1;
    c1.x = sigmoidf_(gf.x) * c0v.x + sigmoidf_(gi.x) * tanhf(gg.x);
    c1.y = sigmoidf_(gf.y) * c0v.y + sigmoidf_(gi.y) * tanhf(gg.y);
    c1.z = sigmoidf_(gf.z) * c0v.z + sigmoidf_(gi.z) * tanhf(gg.z);
    c1.w = sigmoidf_(gf.w) * c0v.w + sigmoidf_(gi.w) * tanhf(gg.w);
    h1.x = sigmoidf_(go.x) * tanhf(c1.x);
    h1.y = sigmoidf_(go.y) * tanhf(c1.y);
    h1.z = sigmoidf_(go.z) * tanhf(c1.z);
    h1.w = sigmoidf_(go.w) * tanhf(c1.w);
    *(float4*)(c1_out + b * 1024 + h) = c1;
    *(float4*)(h1_out + b * 1024 + h) = h1;
    *(float4*)(hcat + b * 2048 + 1024 + h) = h1;   // right half of concat buffer
}

// ---------------- fused masked softmax attention, single pass over ctx (flash-style) ----------------
// grid = 512 (one block per b), 256 threads = 4 waves; wave w owns rows [w*64, w*64+64)
// NOTE: ctx_mask is jnp.bool_ passed by harness as int32 -> read as const int*.
__global__ __launch_bounds__(256) void k_attn(
    const float* __restrict__ ctx, const int* __restrict__ mask,
    const float* __restrict__ target,
    float* __restrict__ alpha, float* __restrict__ wcat)
{
    __shared__ float s_scores[256];
    __shared__ float s_m[4], s_l[4];
    __shared__ float s_acc[4][1024];
    const int b = blockIdx.x;
    const int tid = threadIdx.x;
    const int lane = tid & 63, wave = tid >> 6;
    const float* ctxb = ctx + (long)b * 256 * 1024;

    float4 tg[4];
    #pragma unroll
    for (int i = 0; i < 4; ++i)
        tg[i] = *(const float4*)(target + b * 1024 + i * 256 + lane * 4);

    float m = -INFINITY, l = 0.f;
    float4 acc[4];
    #pragma unroll
    for (int i = 0; i < 4; ++i) acc[i] = make_float4(0.f, 0.f, 0.f, 0.f);

    const int j0 = wave * 64;
    float4 cv[4], cn[4];
    {
        const float* rp = ctxb + (long)j0 * 1024;
        #pragma unroll
        for (int i = 0; i < 4; ++i) cv[i] = *(const float4*)(rp + i * 256 + lane * 4);
    }
    for (int r = 0; r < 64; ++r) {
        const int j = j0 + r;
        if (r < 63) {
            const float* np = ctxb + (long)(j + 1) * 1024;
            #pragma unroll
            for (int i = 0; i < 4; ++i) cn[i] = *(const float4*)(np + i * 256 + lane * 4);
        }
        float part = 0.f;
        #pragma unroll
        for (int i = 0; i < 4; ++i) {
            part = fmaf(cv[i].x, tg[i].x, part);
            part = fmaf(cv[i].y, tg[i].y, part);
            part = fmaf(cv[i].z, tg[i].z, part);
            part = fmaf(cv[i].w, tg[i].w, part);
        }
        #pragma unroll
        for (int off = 32; off; off >>= 1) part += __shfl_xor(part, off);
        const bool msk = mask[b * 256 + j] != 0;
        float s = msk ? -INFINITY : part;
        if (lane == 0) s_scores[j] = s;
        if (!msk) {
            if (s > m) {
                float sc = expf(m - s);     // exp(-inf)=0 on first hit: clean reset
                l *= sc;
                #pragma unroll
                for (int i = 0; i < 4; ++i) {
                    acc[i].x *= sc; acc[i].y *= sc; acc[i].z *= sc; acc[i].w *= sc;
                }
                m = s;
            }
            float e = expf(s - m);
            l += e;
            #pragma unroll
            for (int i = 0; i < 4; ++i) {
                acc[i].x = fmaf(e, cv[i].x, acc[i].x);
                acc[i].y = fmaf(e, cv[i].y, acc[i].y);
                acc[i].z = fmaf(e, cv[i].z, acc[i].z);
                acc[i].w = fmaf(e, cv[i].w, acc[i].w);
            }
        }
        #pragma unroll
        for (int i = 0; i < 4; ++i) cv[i] = cn[i];
    }
    if (lane == 0) { s_m[wave] = m; s_l[wave] = l; }
    #pragma unroll
    for (int i = 0; i < 4; ++i)
        *(float4*)&s_acc[wave][i * 256 + lane * 4] = acc[i];
    __syncthreads();

    const float mg = fmaxf(fmaxf(s_m[0], s_m[1]), fmaxf(s_m[2], s_m[3]));
    float ew[4], lg = 0.f;
    #pragma unroll
    for (int w = 0; w < 4; ++w) { ew[w] = expf(s_m[w] - mg); lg += s_l[w] * ew[w]; }
    const float inv = 1.0f / lg;

    // weighted -> left half of concat buffer; each thread owns 4 consecutive d
    float4 wsum = make_float4(0.f, 0.f, 0.f, 0.f);
    #pragma unroll
    for (int w = 0; w < 4; ++w) {
        float4 t = *(float4*)&s_acc[w][tid * 4];
        wsum.x = fmaf(ew[w], t.x, wsum.x);
        wsum.y = fmaf(ew[w], t.y, wsum.y);
        wsum.z = fmaf(ew[w], t.z, wsum.z);
        wsum.w = fmaf(ew[w], t.w, wsum.w);
    }
    wsum.x *= inv; wsum.y *= inv; wsum.z *= inv; wsum.w *= inv;
    *(float4*)(wcat + (long)b * 2048 + tid * 4) = wsum;

    alpha[b * 256 + tid] = expf(s_scores[tid] - mg) * inv;
}

// ---------------- decoder: logit[512,14] = h_tilde @ W_dec^T + b_dec ----------------
__global__ __launch_bounds__(256) void k_dec(
    const float* __restrict__ ht, const float* __restrict__ Wd,
    const float* __restrict__ bd, float* __restrict__ logit)
{
    const int b = blockIdx.x * 4 + (threadIdx.x >> 6);
    const int lane = threadIdx.x & 63;
    float h[16];
    #pragma unroll
    for (int i = 0; i < 16; ++i) h[i] = ht[b * 1024 + i * 64 + lane];
    for (int j = 0; j < 14; ++j) {
        float p = 0.f;
        #pragma unroll
        for (int i = 0; i < 16; ++i) p = fmaf(h[i], Wd[j * 1024 + i * 64 + lane], p);
        #pragma unroll
        for (int off = 32; off; off >>= 1) p += __shfl_xor(p, off);
        if (lane == 0) logit[b * 14 + j] = p + bd[j];
    }
}

extern "C" void kernel_launch(void* const* d_in, const int* in_sizes, int n_in,
                              void* d_out, int out_size, void* d_ws, size_t ws_size,
                              hipStream_t stream) {
    const int* action    = (const int*)d_in[0];
    const float* feature = (const float*)d_in[1];
    const float* h0      = (const float*)d_in[2];
    const float* c0      = (const float*)d_in[3];
    const float* ctx     = (const float*)d_in[4];
    const int* mask      = (const int*)d_in[5];
    const float* emb     = (const float*)d_in[6];
    const float* W_ih    = (const float*)d_in[7];
    const float* W_hh    = (const float*)d_in[8];
    const float* b_ih    = (const float*)d_in[9];
    const float* b_hh    = (const float*)d_in[10];
    const float* W_in    = (const float*)d_in[11];
    const float* W_out   = (const float*)d_in[12];
    const float* W_dec   = (const float*)d_in[13];
    const float* b_dec   = (const float*)d_in[14];

    float* out   = (float*)d_out;
    float* h1    = out;
    float* c1    = out + 524288;
    float* alpha = out + 1048576;
    float* logit = out + 1179648;

    float* ws     = (float*)d_ws;
    float* wcat   = ws;                 // [512][2048] f32
    float* gates  = ws + 1048576;       // [512][4096]
    float* xh     = ws + 3145728;       // [512][1792]
    float* target = ws + 3145728;       // reuses xh region (xh dead by then)
    float* htld   = ws + 3670016;       // [512][1024]

    // 1. xh = [emb | feature | h0]
    k_build_xh<<<896, 256, 0, stream>>>(action, feature, h0, emb, xh);

    // 2. gates = xh[:, :768] @ W_ih^T + xh[:, 768:] @ W_hh^T + (b_ih + b_hh)   [bf16 MFMA]
    dim3 g1(8, 64);
    k_gemm_mfma<true, false><<<g1, 256, 0, stream>>>(
        xh, 1792, W_ih, 768, 768,
        xh + 768, 1792, W_hh, 1024, 1024,
        gates, 4096, b_ih, b_hh);

    // 3. LSTM cell -> h1, c1 (out) + h1 into right half of wcat
    k_lstm<<<512, 256, 0, stream>>>(gates, c0, h1, c1, wcat);

    // 4. target = h1 @ W_in^T   [f32: feeds peaked softmax]
    dim3 g2(8, 16);
    k_gemm_nt_f32<<<g2, 256, 0, stream>>>(
        wcat + 1024, 2048, W_in, 1024, 1024,
        target, 1024);

    // 5. masked-softmax attention (single ctx pass) -> alpha (out) + weighted into left half of wcat
    k_attn<<<512, 256, 0, stream>>>(ctx, mask, target, alpha, wcat);

    // 6. h_tilde = tanh([weighted | h1] @ W_out^T)   [bf16 MFMA, K=2048 over concat buffer]
    k_gemm_mfma<false, true><<<g2, 256, 0, stream>>>(
        wcat, 2048, W_out, 2048, 2048,
        nullptr, 0, nullptr, 0, 0,
        htld, 1024, nullptr, nullptr);

    // 7. logit = h_tilde @ W_dec^T + b_dec
    k_dec<<<128, 256, 0, stream>>>(htld, W_dec, b_dec, logit);
}